// Round 1
// baseline (2091.521 us; speedup 1.0000x reference)
//
#include <hip/hip_runtime.h>
#include <cstddef>

// Problem constants
#define BB 16
#define HH 256
#define CC 128
#define WW 128
#define LDA 132              // padded LDS row stride (floats); 132%4==0 keeps float4 alignment
#define R2  (128 * LDA)      // second LDS region offset (floats) = 16896
#define LDS_FLOATS (256 * LDA)  // 33792 floats = 135168 B

__device__ __forceinline__ void ld8(float d[8], const float* p) {
    float4 a = *(const float4*)p;
    float4 b = *(const float4*)(p + 4);
    d[0]=a.x; d[1]=a.y; d[2]=a.z; d[3]=a.w;
    d[4]=b.x; d[5]=b.y; d[6]=b.z; d[7]=b.w;
}

__device__ __forceinline__ void fma8x8(float acc[8][8], const float af[8], const float bf[8]) {
#pragma unroll
    for (int i = 0; i < 8; ++i)
#pragma unroll
        for (int j = 0; j < 8; ++j)
            acc[i][j] = fmaf(af[i], bf[j], acc[i][j]);
}

__device__ __forceinline__ void zero8x8(float acc[8][8]) {
#pragma unroll
    for (int i = 0; i < 8; ++i)
#pragma unroll
        for (int j = 0; j < 8; ++j) acc[i][j] = 0.f;
}

// Generic (p,q) transpose: src[((b*P+p)*C+c)*Q+q] -> dst[((b*Q+q)*C+c)*P+p]
// T1: P=HH,Q=WW (x -> X_t). T2: P=WW,Q=HH (out_t -> out).
__global__ __launch_bounds__(256) void transpose_pq(const float* __restrict__ src,
                                                    float* __restrict__ dst,
                                                    int P, int Q) {
    __shared__ float tile[32][33];
    const int QT = Q >> 5, PT = P >> 5;
    int bx = blockIdx.x;
    const int qt = bx % QT; bx /= QT;
    const int pt = bx % PT; bx /= PT;
    const int c  = bx % CC;
    const int b  = bx / CC;
    const int tx = threadIdx.x & 31, ty = threadIdx.x >> 5;

    size_t sbase = (((size_t)b * P + pt * 32) * CC + c) * Q + qt * 32;
#pragma unroll
    for (int k = 0; k < 4; ++k) {
        int i = ty + 8 * k;
        tile[i][tx] = src[sbase + (size_t)i * CC * Q + tx];
    }
    __syncthreads();
    size_t dbase = (((size_t)b * Q + qt * 32) * CC + c) * P + pt * 32;
#pragma unroll
    for (int k = 0; k < 4; ++k) {
        int i = ty + 8 * k;
        dst[dbase + (size_t)i * CC * P + tx] = tile[tx][i];
    }
}

// P1: per (b,w): G = X X^T, r = X*1, S = (Wq^T G Wk + rank-1 bias terms)/sqrt(W)
__global__ __launch_bounds__(256) void p1_kernel(const float* __restrict__ Xt,
                                                 const float* __restrict__ Wq,
                                                 const float* __restrict__ bq,
                                                 const float* __restrict__ Wk,
                                                 const float* __restrict__ bk,
                                                 float* __restrict__ Sout) {
    __shared__ __align__(16) float lds[LDS_FLOATS];
    __shared__ float rbuf[128], rqb[128], rkb[128];
    const int tid = threadIdx.x;
    const int w = blockIdx.x, b = blockIdx.y;
    const float* Xg = Xt + (size_t)(b * WW + w) * (CC * HH);

    // Stage X into LDS as xs[h][c] (transpose-on-load; coalesced global reads)
    for (int l = tid; l < CC * HH; l += 256) {
        int c = l >> 8, h = l & 255;
        lds[h * LDA + c] = Xg[l];
    }
    __syncthreads();

    const int ty = tid >> 4, tx = tid & 15;
    const int r0 = ty * 8, c0 = tx * 8;
    float acc[8][8];

    // --- G = X X^T ---
    zero8x8(acc);
#pragma unroll 4
    for (int h = 0; h < HH; ++h) {
        float af[8], bf[8];
        ld8(af, &lds[h * LDA + r0]);
        ld8(bf, &lds[h * LDA + c0]);
        fma8x8(acc, af, bf);
    }
    // r[c] = sum_h X[c,h]
    float rv = 0.f;
    if (tid < 128) {
        for (int h = 0; h < HH; ++h) rv += lds[h * LDA + tid];
    }
    __syncthreads();   // all xs reads complete
    if (tid < 128) rbuf[tid] = rv;
    // write G into region1 (rows c, cols c2)
#pragma unroll
    for (int i = 0; i < 8; ++i) {
        *(float4*)&lds[(r0 + i) * LDA + c0]     = make_float4(acc[i][0], acc[i][1], acc[i][2], acc[i][3]);
        *(float4*)&lds[(r0 + i) * LDA + c0 + 4] = make_float4(acc[i][4], acc[i][5], acc[i][6], acc[i][7]);
    }
    __syncthreads();

    // rq = Wq^T r ; rk = Wk^T r
    if (tid < 128) {
        float s = 0.f;
        for (int c = 0; c < CC; ++c) s = fmaf(Wq[c * CC + tid], rbuf[c], s);
        rqb[tid] = s;
    } else {
        int d = tid - 128;
        float s = 0.f;
        for (int c = 0; c < CC; ++c) s = fmaf(Wk[c * CC + d], rbuf[c], s);
        rkb[d] = s;
    }

    // --- T = Wq^T G : T[dq,c2] ---
    zero8x8(acc);
#pragma unroll 4
    for (int c = 0; c < CC; ++c) {
        float af[8], bf[8];
        ld8(af, &Wq[c * CC + r0]);      // Wq[c, dq]
        ld8(bf, &lds[c * LDA + c0]);    // G[c, c2]
        fma8x8(acc, af, bf);
    }
    // write T transposed into region2: T_t[c2][dq]
#pragma unroll
    for (int i = 0; i < 8; ++i)
#pragma unroll
        for (int j = 0; j < 8; ++j)
            lds[R2 + (c0 + j) * LDA + (r0 + i)] = acc[i][j];
    __syncthreads();

    // --- S = T * Wk : S[dq,dk] ---
    zero8x8(acc);
#pragma unroll 4
    for (int c2 = 0; c2 < CC; ++c2) {
        float af[8], bf[8];
        ld8(af, &lds[R2 + c2 * LDA + r0]);  // T[dq, c2]
        ld8(bf, &Wk[c2 * CC + c0]);         // Wk[c2, dk]
        fma8x8(acc, af, bf);
    }
    const float inv_scale = 0.08838834764831845f;  // 1/sqrt(128)
    float* Sg = Sout + (size_t)(b * WW + w) * (CC * CC);
#pragma unroll
    for (int i = 0; i < 8; ++i) {
        float q1 = bq[r0 + i], q2 = rqb[r0 + i];
        float row[8];
#pragma unroll
        for (int j = 0; j < 8; ++j) {
            float kb = bk[c0 + j], kr = rkb[c0 + j];
            row[j] = (acc[i][j] + q2 * kb + q1 * kr + (float)HH * q1 * kb) * inv_scale;
        }
        *(float4*)&Sg[(r0 + i) * CC + c0]     = make_float4(row[0], row[1], row[2], row[3]);
        *(float4*)&Sg[(r0 + i) * CC + c0 + 4] = make_float4(row[4], row[5], row[6], row[7]);
    }
}

// P2: online softmax stats over w. z[b,c,d] = max + log(sum exp(. - max))
__global__ __launch_bounds__(256) void p2_kernel(const float* __restrict__ S,
                                                 float* __restrict__ z) {
    int i = blockIdx.x * 256 + threadIdx.x;   // i < BB*CC*CC = 262144
    int b = i >> 14, cd = i & 16383;
    const float* p = S + (size_t)b * WW * CC * CC + cd;
    float m = -1e30f, l = 0.f;
    for (int w = 0; w < WW; ++w) {
        float s = p[(size_t)w * CC * CC];
        if (s > m) { l = fmaf(l, __expf(m - s), 1.f); m = s; }
        else       { l += __expf(s - m); }
    }
    z[i] = m + __logf(l);
}

// P3: per (b,w): A = exp(S - z); WN = A*Wn + bn; Y = WN*Wv^T; P = Wo^T*Y;
//     O = P*X + u*1^T, u = Wo^T(WN*bv)+bo.  O written over the X_t slice.
__global__ __launch_bounds__(256) void p3_kernel(float* __restrict__ XtO,
                                                 const float* __restrict__ Sin,
                                                 const float* __restrict__ Zin,
                                                 const float* __restrict__ Wnm,
                                                 const float* __restrict__ bn,
                                                 const float* __restrict__ Wv,
                                                 const float* __restrict__ bv,
                                                 const float* __restrict__ Wo,
                                                 const float* __restrict__ bo) {
    __shared__ __align__(16) float lds[LDS_FLOATS];
    __shared__ float sbuf[128], ubuf[128];
    const int tid = threadIdx.x;
    const int w = blockIdx.x, b = blockIdx.y;
    const float* Sg = Sin + (size_t)(b * WW + w) * (CC * CC);
    const float* Zb = Zin + (size_t)b * (CC * CC);
    float* Xg = XtO + (size_t)(b * WW + w) * (CC * HH);

    // A_t[d][c] = exp(S[c,d] - z[c,d])  -> region1
    for (int l = tid; l < CC * CC; l += 256) {
        int c = l >> 7, d = l & 127;
        lds[d * LDA + c] = __expf(Sg[l] - Zb[l]);
    }
    __syncthreads();

    const int ty = tid >> 4, tx = tid & 15;
    const int r0 = ty * 8, c0 = tx * 8;
    float acc[8][8];

    // --- WN[c,e] = sum_d A[c,d]*Wn[d,e] + bn[e] ---
    zero8x8(acc);
#pragma unroll 4
    for (int d = 0; d < CC; ++d) {
        float af[8], bf[8];
        ld8(af, &lds[d * LDA + r0]);     // A[c,d] via A_t
        ld8(bf, &Wnm[d * CC + c0]);      // Wn[d,e]
        fma8x8(acc, af, bf);
    }
#pragma unroll
    for (int j = 0; j < 8; ++j) {
        float bnv = bn[c0 + j];
#pragma unroll
        for (int i = 0; i < 8; ++i) acc[i][j] += bnv;
    }
    __syncthreads();   // region1 (A_t) reads done

    // WN_t[e][c] -> region2 ; Wv_t[e][c2] -> region1
#pragma unroll
    for (int i = 0; i < 8; ++i)
#pragma unroll
        for (int j = 0; j < 8; ++j)
            lds[R2 + (c0 + j) * LDA + (r0 + i)] = acc[i][j];
    for (int l = tid; l < CC * CC; l += 256) {
        int c2 = l >> 7, e = l & 127;
        lds[e * LDA + c2] = Wv[l];
    }
    __syncthreads();

    // --- Y[c,c2] = sum_e WN[c,e]*Wv[c2,e] ; t1[c] = sum_e WN[c,e]*bv[e] ---
    zero8x8(acc);
#pragma unroll 4
    for (int e = 0; e < CC; ++e) {
        float af[8], bf[8];
        ld8(af, &lds[R2 + e * LDA + r0]);   // WN[c,e] via WN_t
        ld8(bf, &lds[e * LDA + c0]);        // Wv[c2,e] via Wv_t
        fma8x8(acc, af, bf);
    }
    if (tid < 128) {
        float t = 0.f;
        for (int e = 0; e < CC; ++e) t = fmaf(lds[R2 + e * LDA + tid], bv[e], t);
        sbuf[tid] = t;
    }
    __syncthreads();   // region1/region2 reads done

    // Y rows -> region1
#pragma unroll
    for (int i = 0; i < 8; ++i) {
        *(float4*)&lds[(r0 + i) * LDA + c0]     = make_float4(acc[i][0], acc[i][1], acc[i][2], acc[i][3]);
        *(float4*)&lds[(r0 + i) * LDA + c0 + 4] = make_float4(acc[i][4], acc[i][5], acc[i][6], acc[i][7]);
    }
    __syncthreads();

    // --- P[o,c2] = sum_c Wo[c,o]*Y[c,c2] ---
    zero8x8(acc);
#pragma unroll 4
    for (int c = 0; c < CC; ++c) {
        float af[8], bf[8];
        ld8(af, &Wo[c * CC + r0]);       // Wo[c,o]
        ld8(bf, &lds[c * LDA + c0]);     // Y[c,c2]
        fma8x8(acc, af, bf);
    }
    __syncthreads();   // region1 (Y) reads done

    // P_t[c2][o] -> region2 ; u[o] ; stage X half0 -> region1
#pragma unroll
    for (int i = 0; i < 8; ++i)
#pragma unroll
        for (int j = 0; j < 8; ++j)
            lds[R2 + (c0 + j) * LDA + (r0 + i)] = acc[i][j];
    if (tid < 128) {
        float t = 0.f;
        for (int c = 0; c < CC; ++c) t = fmaf(Wo[c * CC + tid], sbuf[c], t);
        ubuf[tid] = t + bo[tid];
    }
    for (int l = tid; l < CC * 128; l += 256) {
        int c2 = l >> 7, hh = l & 127;
        lds[c2 * LDA + hh] = Xg[c2 * HH + hh];
    }
    __syncthreads();

    // --- O half0: O[o,h] = sum_c2 P[o,c2]*X[c2,h], h in [0,128) ---
    zero8x8(acc);
#pragma unroll 4
    for (int c2 = 0; c2 < CC; ++c2) {
        float af[8], bf[8];
        ld8(af, &lds[R2 + c2 * LDA + r0]);  // P[o,c2] via P_t
        ld8(bf, &lds[c2 * LDA + c0]);       // X[c2,h]
        fma8x8(acc, af, bf);
    }
#pragma unroll
    for (int i = 0; i < 8; ++i) {
        float u = ubuf[r0 + i];
        *(float4*)&Xg[(r0 + i) * HH + c0]     = make_float4(acc[i][0]+u, acc[i][1]+u, acc[i][2]+u, acc[i][3]+u);
        *(float4*)&Xg[(r0 + i) * HH + c0 + 4] = make_float4(acc[i][4]+u, acc[i][5]+u, acc[i][6]+u, acc[i][7]+u);
    }
    __syncthreads();   // all region1 reads done before restaging

    // stage X half1 (h in [128,256)) -> region1 (disjoint from half0 writes)
    for (int l = tid; l < CC * 128; l += 256) {
        int c2 = l >> 7, hh = l & 127;
        lds[c2 * LDA + hh] = Xg[c2 * HH + 128 + hh];
    }
    __syncthreads();

    // --- O half1 ---
    zero8x8(acc);
#pragma unroll 4
    for (int c2 = 0; c2 < CC; ++c2) {
        float af[8], bf[8];
        ld8(af, &lds[R2 + c2 * LDA + r0]);
        ld8(bf, &lds[c2 * LDA + c0]);
        fma8x8(acc, af, bf);
    }
#pragma unroll
    for (int i = 0; i < 8; ++i) {
        float u = ubuf[r0 + i];
        *(float4*)&Xg[(r0 + i) * HH + 128 + c0]     = make_float4(acc[i][0]+u, acc[i][1]+u, acc[i][2]+u, acc[i][3]+u);
        *(float4*)&Xg[(r0 + i) * HH + 128 + c0 + 4] = make_float4(acc[i][4]+u, acc[i][5]+u, acc[i][6]+u, acc[i][7]+u);
    }
}

extern "C" void kernel_launch(void* const* d_in, const int* in_sizes, int n_in,
                              void* d_out, int out_size, void* d_ws, size_t ws_size,
                              hipStream_t stream) {
    const float* x  = (const float*)d_in[0];
    const float* Wq = (const float*)d_in[1];
    const float* bq = (const float*)d_in[2];
    const float* Wk = (const float*)d_in[3];
    const float* bk = (const float*)d_in[4];
    const float* Wv = (const float*)d_in[5];
    const float* bv = (const float*)d_in[6];
    const float* Wn = (const float*)d_in[7];
    const float* bn = (const float*)d_in[8];
    const float* Wo = (const float*)d_in[9];
    const float* bo = (const float*)d_in[10];
    float* out = (float*)d_out;

    float* wsX = (float*)d_ws;                    // (B,W,C,H) X_t, later out_t: 67108864 floats
    float* wsS = wsX + (size_t)BB * WW * CC * HH; // scores (B,W,C,C): 33554432 floats
    float* wsZ = wsS + (size_t)BB * WW * CC * CC; // softmax z (B,C,C): 262144 floats

    // T1: x (B,H,C,W) -> X_t (B,W,C,H)
    transpose_pq<<<BB * CC * (HH / 32) * (WW / 32), 256, 0, stream>>>(x, wsX, HH, WW);
    // P1: scores
    p1_kernel<<<dim3(WW, BB), 256, 0, stream>>>(wsX, Wq, bq, Wk, bk, wsS);
    // P2: softmax stats over w
    p2_kernel<<<(BB * CC * CC) / 256, 256, 0, stream>>>(wsS, wsZ);
    // P3: attn chain, writes out_t over X_t region
    p3_kernel<<<dim3(WW, BB), 256, 0, stream>>>(wsX, wsS, wsZ, Wn, bn, Wv, bv, Wo, bo);
    // T2: out_t (B,W,C,H) -> out (B,H,C,W)
    transpose_pq<<<BB * CC * (WW / 32) * (HH / 32), 256, 0, stream>>>(wsX, out, WW, HH);
}

// Round 2
// 739.806 us; speedup vs baseline: 2.8271x; 2.8271x over previous
//
#include <hip/hip_runtime.h>
#include <cstddef>

// Problem constants
#define BB 16
#define HH 256
#define CC 128
#define WW 128

typedef _Float16 f16;
typedef _Float16 f16x8 __attribute__((ext_vector_type(8)));
typedef _Float16 f16x4 __attribute__((ext_vector_type(4)));
typedef float f32x4 __attribute__((ext_vector_type(4)));

#define LD1 136   // padded ld (f16) for K=128 operands: 272B stride -> 2-way max on b128 frag reads
#define LDX 264   // padded ld (f16) for K=256 X operand in P1
#define LDP 140   // plain-X ld for P3 GEMM-4 (scalar B reads): 280B stride -> quad rows split banks
#define REG 17920 // f16 elems per LDS region (= 128*LDP, >= 128*LD1)

__device__ __forceinline__ void zero_acc(f32x4 acc[4][4]) {
#pragma unroll
    for (int i = 0; i < 4; ++i)
#pragma unroll
        for (int j = 0; j < 4; ++j) acc[i][j] = (f32x4){0.f, 0.f, 0.f, 0.f};
}

// C[128x128] += A(128xK, lds) * B^T-layout(Bt[n][k], lds). Wave covers 64x64 (4x4 tiles 16x16).
__device__ __forceinline__ void gemm_ab(const f16* __restrict__ A, int lda,
                                        const f16* __restrict__ B, int ldb,
                                        int K, int m0, int n0, int l15, int quad,
                                        f32x4 acc[4][4]) {
    for (int kc = 0; kc < K; kc += 32) {
        f16x8 af[4], bf[4];
        const f16* ap = A + (size_t)(m0 + l15) * lda + kc + quad * 8;
        const f16* bp = B + (size_t)(n0 + l15) * ldb + kc + quad * 8;
#pragma unroll
        for (int t = 0; t < 4; ++t) {
            af[t] = *(const f16x8*)(ap + t * 16 * lda);
            bf[t] = *(const f16x8*)(bp + t * 16 * ldb);
        }
#pragma unroll
        for (int mt = 0; mt < 4; ++mt)
#pragma unroll
            for (int nt = 0; nt < 4; ++nt)
                acc[mt][nt] = __builtin_amdgcn_mfma_f32_16x16x32_f16(af[mt], bf[nt], acc[mt][nt], 0, 0, 0);
    }
}

// Same, but B is stored PLAIN row-major [k][n] (scalar ds reads for B fragments). K=128 fixed.
__device__ __forceinline__ void gemm_a_bplain(const f16* __restrict__ A, int lda,
                                              const f16* __restrict__ Bp, int ldb,
                                              int m0, int n0, int l15, int quad,
                                              f32x4 acc[4][4]) {
    for (int kc = 0; kc < 128; kc += 32) {
        f16x8 af[4];
        const f16* ap = A + (size_t)(m0 + l15) * lda + kc + quad * 8;
#pragma unroll
        for (int t = 0; t < 4; ++t) af[t] = *(const f16x8*)(ap + t * 16 * lda);
#pragma unroll
        for (int nt = 0; nt < 4; ++nt) {
            f16x8 bv;
            const f16* bp = Bp + (size_t)(kc + quad * 8) * ldb + n0 + nt * 16 + l15;
#pragma unroll
            for (int j = 0; j < 8; ++j) bv[j] = bp[j * ldb];
#pragma unroll
            for (int mt = 0; mt < 4; ++mt)
                acc[mt][nt] = __builtin_amdgcn_mfma_f32_16x16x32_f16(af[mt], bv, acc[mt][nt], 0, 0, 0);
        }
    }
}

// Transpose-stage C regs -> LDS dst[col][row] (f16). 4 consecutive rows/lane -> ds_write_b64.
__device__ __forceinline__ void stage_ct(const f32x4 acc[4][4], f16* dst, int ld,
                                         int m0, int n0, int l15, int quad) {
#pragma unroll
    for (int mt = 0; mt < 4; ++mt)
#pragma unroll
        for (int nt = 0; nt < 4; ++nt) {
            f16x4 v;
#pragma unroll
            for (int r = 0; r < 4; ++r) v[r] = (f16)acc[mt][nt][r];
            int col = n0 + nt * 16 + l15;
            int row = m0 + mt * 16 + quad * 4;
            *(f16x4*)(dst + (size_t)col * ld + row) = v;
        }
}

// Copy a prepacked 128x128 f16 matrix from global into padded LDS region.
__device__ __forceinline__ void stage_w(const f16* __restrict__ g, f16* dst, int tid) {
#pragma unroll
    for (int i = 0; i < 8; ++i) {
        int idx = tid + i * 256;
        int row = idx >> 4, cc = (idx & 15) * 8;
        *(f16x8*)(dst + row * LD1 + cc) = *(const f16x8*)(g + row * 128 + cc);
    }
}

// Prepack weights to f16: [0]=WqT, [1]=WkT, [2]=WnT, [3]=Wv, [4]=WoT (each 128x128)
__global__ __launch_bounds__(256) void prep_w(const float* __restrict__ Wq, const float* __restrict__ Wk,
                                              const float* __restrict__ Wn, const float* __restrict__ Wv,
                                              const float* __restrict__ Wo, f16* __restrict__ out) {
    int id = blockIdx.x * 256 + threadIdx.x;  // < 5*16384
    int m = id >> 14;
    int r = (id >> 7) & 127, c = id & 127;
    float v;
    if (m == 0)      v = Wq[c * 128 + r];
    else if (m == 1) v = Wk[c * 128 + r];
    else if (m == 2) v = Wn[c * 128 + r];
    else if (m == 3) v = Wv[r * 128 + c];
    else             v = Wo[c * 128 + r];
    out[id] = (f16)v;
}

// T1: x fp32 (B,H,C,W) -> X_t f16 (B,W,C,H)
__global__ __launch_bounds__(256) void t1_k(const float* __restrict__ src, f16* __restrict__ dst) {
    __shared__ float tile[32][33];
    int bx = blockIdx.x;
    const int qt = bx & 3;  bx >>= 2;   // W/32
    const int pt = bx & 7;  bx >>= 3;   // H/32
    const int c  = bx & 127;
    const int b  = bx >> 7;
    const int tx = threadIdx.x & 31, ty = threadIdx.x >> 5;
    size_t sbase = (((size_t)b * HH + pt * 32) * CC + c) * WW + qt * 32;
#pragma unroll
    for (int k = 0; k < 4; ++k) {
        int i = ty + 8 * k;
        tile[i][tx] = src[sbase + (size_t)i * CC * WW + tx];
    }
    __syncthreads();
    size_t dbase = (((size_t)b * WW + qt * 32) * CC + c) * HH + pt * 32;
#pragma unroll
    for (int k = 0; k < 4; ++k) {
        int i = ty + 8 * k;
        dst[dbase + (size_t)i * CC * HH + tx] = (f16)tile[tx][i];
    }
}

// T2: O f16 (B,W,C,H) -> out fp32 (B,H,C,W)
__global__ __launch_bounds__(256) void t2_k(const f16* __restrict__ src, float* __restrict__ dst) {
    __shared__ float tile[32][33];
    int bx = blockIdx.x;
    const int ht = bx & 7;  bx >>= 3;   // H/32
    const int wt = bx & 3;  bx >>= 2;   // W/32
    const int c  = bx & 127;
    const int b  = bx >> 7;
    const int tx = threadIdx.x & 31, ty = threadIdx.x >> 5;
    size_t sbase = (((size_t)b * WW + wt * 32) * CC + c) * HH + ht * 32;
#pragma unroll
    for (int k = 0; k < 4; ++k) {
        int i = ty + 8 * k;          // w offset
        tile[i][tx] = (float)src[sbase + (size_t)i * CC * HH + tx];  // tx = h offset
    }
    __syncthreads();
    size_t dbase = (((size_t)b * HH + ht * 32) * CC + c) * WW + wt * 32;
#pragma unroll
    for (int k = 0; k < 4; ++k) {
        int i = ty + 8 * k;          // h offset
        dst[dbase + (size_t)i * CC * WW + tx] = tile[tx][i];         // tx = w offset
    }
}

// P1 per (b,w): G = X X^T (K=256); Tt = G^T(=G) * WqT^T ... -> S = (Wq^T G Wk + rank-1 bias)/sqrt(W)
__global__ __launch_bounds__(256, 2) void p1_kernel(const f16* __restrict__ Xt,
                                                    const f16* __restrict__ Wpk,
                                                    const float* __restrict__ Wq_g, const float* __restrict__ bq,
                                                    const float* __restrict__ Wk_g, const float* __restrict__ bk,
                                                    float* __restrict__ Sout) {
    __shared__ f16 sm[2 * REG];
    __shared__ float rbuf[128], rqb[128], rkb[128];
    const int tid = threadIdx.x;
    const int w = blockIdx.x, b = blockIdx.y;
    const f16* Xg = Xt + (size_t)(b * WW + w) * (CC * HH);
    f16* Xs = sm;          // ld LDX, 128x256
    f16* RA = sm;          // ld LD1
    f16* RB = sm + REG;    // ld LD1

    // stage X [c][h] (f16, straight copy with pad)
#pragma unroll
    for (int i = 0; i < 16; ++i) {
        int g = tid + i * 256;
        int row = g >> 5, cc = (g & 31) * 8;
        *(f16x8*)(Xs + row * LDX + cc) = *(const f16x8*)(Xg + row * 256 + cc);
    }
    __syncthreads();

    const int lane = tid & 63, wid = tid >> 6;
    const int l15 = lane & 15, quad = lane >> 4;
    const int m0 = (wid >> 1) * 64, n0 = (wid & 1) * 64;

    // r[c] = sum_h X[c,h]
    if (tid < 128) {
        float s = 0.f;
        for (int hc = 0; hc < 32; ++hc) {
            f16x8 v = *(const f16x8*)(Xs + tid * LDX + hc * 8);
#pragma unroll
            for (int j = 0; j < 8; ++j) s += (float)v[j];
        }
        rbuf[tid] = s;
    }

    f32x4 acc[4][4];
    zero_acc(acc);
    gemm_ab(Xs, LDX, Xs, LDX, 256, m0, n0, l15, quad, acc);  // G[c][c2]
    __syncthreads();

    stage_ct(acc, RA, LD1, m0, n0, l15, quad);  // Gs[c2][c] (= G, symmetric)
    stage_w(Wpk + 0 * 16384, RB, tid);          // WqT[dq][c]
    if (tid < 128) {                            // rq = Wq^T r
        float s = 0.f;
        for (int c = 0; c < 128; ++c) s = fmaf(Wq_g[c * 128 + tid], rbuf[c], s);
        rqb[tid] = s;
    } else {                                    // rk = Wk^T r
        int d = tid - 128;
        float s = 0.f;
        for (int c = 0; c < 128; ++c) s = fmaf(Wk_g[c * 128 + d], rbuf[c], s);
        rkb[d] = s;
    }
    __syncthreads();

    zero_acc(acc);
    gemm_ab(RA, LD1, RB, LD1, 128, m0, n0, l15, quad, acc);  // Tt[c2][dq] = sum_c G[c][c2] Wq[c][dq]
    __syncthreads();
    stage_ct(acc, RA, LD1, m0, n0, l15, quad);  // Ts[dq][c2]
    stage_w(Wpk + 1 * 16384, RB, tid);          // WkT[dk][c2]
    __syncthreads();

    zero_acc(acc);
    gemm_ab(RA, LD1, RB, LD1, 128, m0, n0, l15, quad, acc);  // S[dq][dk]

    const float inv_scale = 0.08838834764831845f;  // 1/sqrt(128)
    float* Sg = Sout + (size_t)(b * WW + w) * (CC * CC);
#pragma unroll
    for (int mt = 0; mt < 4; ++mt)
#pragma unroll
        for (int r = 0; r < 4; ++r) {
            int dq = m0 + mt * 16 + quad * 4 + r;
            float q1 = bq[dq], q2 = rqb[dq];
#pragma unroll
            for (int nt = 0; nt < 4; ++nt) {
                int dk = n0 + nt * 16 + l15;
                float kb = bk[dk], kr = rkb[dk];
                Sg[dq * 128 + dk] = (acc[mt][nt][r] + q2 * kb + q1 * kr + 256.f * q1 * kb) * inv_scale;
            }
        }
}

// P2: online softmax stats over w. z[b,c,d] = max + log(sum exp(. - max))
__global__ __launch_bounds__(256) void p2_kernel(const float* __restrict__ S,
                                                 float* __restrict__ z) {
    int i = blockIdx.x * 256 + threadIdx.x;   // i < BB*CC*CC
    int b = i >> 14, cd = i & 16383;
    const float* p = S + (size_t)b * WW * CC * CC + cd;
    float m = -1e30f, l = 0.f;
    for (int w = 0; w < WW; ++w) {
        float s = p[(size_t)w * CC * CC];
        if (s > m) { l = fmaf(l, __expf(m - s), 1.f); m = s; }
        else       { l += __expf(s - m); }
    }
    z[i] = m + __logf(l);
}

// P3 per (b,w): A=exp(S-z); WNt = WnT*A^T; Y = WN*Wv^T; Pt = Y_t*WoT^T; O = P*X + u*1^T
__global__ __launch_bounds__(256, 2) void p3_kernel(f16* __restrict__ XtO,
                                                    const float* __restrict__ Sin, const float* __restrict__ Zin,
                                                    const f16* __restrict__ Wpk,
                                                    const float* __restrict__ bn_g, const float* __restrict__ bv_g,
                                                    const float* __restrict__ bo_g) {
    __shared__ f16 sm[2 * REG];
    __shared__ float t1b[128], ub[128];
    const int tid = threadIdx.x;
    const int w = blockIdx.x, b = blockIdx.y;
    const float* Sg = Sin + (size_t)(b * WW + w) * (CC * CC);
    const float* Zb = Zin + (size_t)b * (CC * CC);
    f16* Xg = XtO + (size_t)(b * WW + w) * (CC * HH);
    f16* R0 = sm;
    f16* R1 = sm + REG;

    // As[c][d] = exp(S - z) -> R0
#pragma unroll
    for (int i = 0; i < 16; ++i) {
        int g = tid + i * 256;
        int c = g >> 5, d4 = (g & 31) * 4;
        float4 s4 = *(const float4*)(Sg + c * 128 + d4);
        float4 z4 = *(const float4*)(Zb + c * 128 + d4);
        f16x4 e;
        e[0] = (f16)__expf(s4.x - z4.x);
        e[1] = (f16)__expf(s4.y - z4.y);
        e[2] = (f16)__expf(s4.z - z4.z);
        e[3] = (f16)__expf(s4.w - z4.w);
        *(f16x4*)(R0 + c * LD1 + d4) = e;
    }
    stage_w(Wpk + 2 * 16384, R1, tid);   // WnT[e][d]
    __syncthreads();

    const int lane = tid & 63, wid = tid >> 6;
    const int l15 = lane & 15, quad = lane >> 4;
    const int m0 = (wid >> 1) * 64, n0 = (wid & 1) * 64;

    f32x4 acc[4][4];
    zero_acc(acc);
    gemm_ab(R1, LD1, R0, LD1, 128, m0, n0, l15, quad, acc);  // WNt[e][c]
    // + bn[e] (row index)
#pragma unroll
    for (int mt = 0; mt < 4; ++mt)
#pragma unroll
        for (int r = 0; r < 4; ++r) {
            float bnv = bn_g[m0 + mt * 16 + quad * 4 + r];
#pragma unroll
            for (int nt = 0; nt < 4; ++nt) acc[mt][nt][r] += bnv;
        }
    __syncthreads();
    stage_ct(acc, R0, LD1, m0, n0, l15, quad);  // WNs[c][e]
    stage_w(Wpk + 3 * 16384, R1, tid);          // Wv[c2][e]
    __syncthreads();
    if (tid < 128) {                            // t1[c] = sum_e WN[c][e] bv[e]
        float s = 0.f;
        for (int e = 0; e < 128; ++e) s = fmaf((float)R0[tid * LD1 + e], bv_g[e], s);
        t1b[tid] = s;
    }
    zero_acc(acc);
    gemm_ab(R0, LD1, R1, LD1, 128, m0, n0, l15, quad, acc);  // Y[c][c2]
    __syncthreads();
    stage_ct(acc, R0, LD1, m0, n0, l15, quad);  // Y_t[c2][c]
    stage_w(Wpk + 4 * 16384, R1, tid);          // WoT[o][c]
    __syncthreads();
    if (tid < 128) {                            // u[o] = sum_c Wo[c][o] t1[c] + bo[o]
        float s = 0.f;
        for (int c = 0; c < 128; ++c) s = fmaf((float)R1[tid * LD1 + c], t1b[c], s);
        ub[tid] = s + bo_g[tid];
    }
    zero_acc(acc);
    gemm_ab(R0, LD1, R1, LD1, 128, m0, n0, l15, quad, acc);  // Pt[c2][o]
    __syncthreads();
    stage_ct(acc, R1, LD1, m0, n0, l15, quad);  // Ps[o][c2]
    // X half0 (h in [0,128)) plain [c2][h] -> R0 (ld LDP)
#pragma unroll
    for (int i = 0; i < 16; ++i) {
        int g = tid + i * 256;
        int c2 = g >> 5, cc = (g & 31) * 4;
        *(f16x4*)(R0 + c2 * LDP + cc) = *(const f16x4*)(Xg + c2 * 256 + cc);
    }
    __syncthreads();
    zero_acc(acc);
    gemm_a_bplain(R1, LD1, R0, LDP, m0, n0, l15, quad, acc);  // O[o][0:128]
#pragma unroll
    for (int mt = 0; mt < 4; ++mt)
#pragma unroll
        for (int r = 0; r < 4; ++r) {
            int o = m0 + mt * 16 + quad * 4 + r;
            float u = ub[o];
#pragma unroll
            for (int nt = 0; nt < 4; ++nt) {
                int h = n0 + nt * 16 + l15;
                Xg[o * 256 + h] = (f16)(acc[mt][nt][r] + u);
            }
        }
    __syncthreads();
    // X half1 (h in [128,256)) -> R0 (disjoint from O half0 writes)
#pragma unroll
    for (int i = 0; i < 16; ++i) {
        int g = tid + i * 256;
        int c2 = g >> 5, cc = (g & 31) * 4;
        *(f16x4*)(R0 + c2 * LDP + cc) = *(const f16x4*)(Xg + c2 * 256 + 128 + cc);
    }
    __syncthreads();
    zero_acc(acc);
    gemm_a_bplain(R1, LD1, R0, LDP, m0, n0, l15, quad, acc);  // O[o][128:256]
#pragma unroll
    for (int mt = 0; mt < 4; ++mt)
#pragma unroll
        for (int r = 0; r < 4; ++r) {
            int o = m0 + mt * 16 + quad * 4 + r;
            float u = ub[o];
#pragma unroll
            for (int nt = 0; nt < 4; ++nt) {
                int h = n0 + nt * 16 + l15;
                Xg[o * 256 + 128 + h] = (f16)(acc[mt][nt][r] + u);
            }
        }
}

extern "C" void kernel_launch(void* const* d_in, const int* in_sizes, int n_in,
                              void* d_out, int out_size, void* d_ws, size_t ws_size,
                              hipStream_t stream) {
    const float* x  = (const float*)d_in[0];
    const float* Wq = (const float*)d_in[1];
    const float* bq = (const float*)d_in[2];
    const float* Wk = (const float*)d_in[3];
    const float* bk = (const float*)d_in[4];
    const float* Wv = (const float*)d_in[5];
    const float* bv = (const float*)d_in[6];
    const float* Wn = (const float*)d_in[7];
    const float* bn = (const float*)d_in[8];
    const float* Wo = (const float*)d_in[9];
    const float* bo = (const float*)d_in[10];
    float* out = (float*)d_out;

    f16*   wsX = (f16*)d_ws;                                     // (B,W,C,H) f16: 134217728 B
    float* wsS = (float*)((char*)d_ws + 134217728);              // scores fp32: 134217728 B
    float* wsZ = (float*)((char*)d_ws + 268435456);              // softmax z: 1 MB
    f16*   wsW = (f16*)((char*)d_ws + 268435456 + 1048576);      // packed weights: 160 KB

    prep_w<<<320, 256, 0, stream>>>(Wq, Wk, Wn, Wv, Wo, wsW);
    t1_k<<<BB * CC * 8 * 4, 256, 0, stream>>>(x, wsX);
    p1_kernel<<<dim3(WW, BB), 256, 0, stream>>>(wsX, wsW, Wq, bq, Wk, bk, wsS);
    p2_kernel<<<(BB * CC * CC) / 256, 256, 0, stream>>>(wsS, wsZ);
    p3_kernel<<<dim3(WW, BB), 256, 0, stream>>>(wsX, wsS, wsZ, wsW, bn, bv, bo);
    t2_k<<<BB * CC * 4 * 8, 256, 0, stream>>>(wsX, out);
}